// Round 14
// baseline (317.092 us; speedup 1.0000x reference)
//
#include <hip/hip_runtime.h>

#define NN 50000
#define EE 800000
#define DD 64
#define GG 512
#define TILES 782          // ceil(NN/64)
#define SCAN_BLOCKS 98     // ceil(NN/512)

typedef __attribute__((ext_vector_type(8))) short short8;
typedef __attribute__((ext_vector_type(4))) float f32x4;

// ---- bf16 helpers ----
__device__ __forceinline__ float b2f(unsigned short u) {
    union { unsigned int i; float f; } c;
    c.i = ((unsigned int)u) << 16;
    return c.f;
}
__device__ __forceinline__ unsigned short f2b(float f) {
    union { float f; unsigned int i; } c;
    c.f = f;
    const unsigned int r = c.i + 0x7FFFu + ((c.i >> 16) & 1u);  // rne
    return (unsigned short)(r >> 16);
}

// ===========================================================================
// prep: x fp32 -> bf16 + zeroing (counts, stats, xpool) + weight swizzle
// (last 6 blocks).
// ===========================================================================
__global__ __launch_bounds__(256) void prep_kernel(const float* __restrict__ x,
                                                   unsigned short* __restrict__ xbf,
                                                   int* __restrict__ counts,
                                                   float* __restrict__ zblock,
                                                   const float* __restrict__ w0,
                                                   const float* __restrict__ w1,
                                                   const float* __restrict__ w2,
                                                   const float* __restrict__ w3,
                                                   const float* __restrict__ w4,
                                                   const float* __restrict__ w5,
                                                   unsigned short* __restrict__ wfrag) {
    if (blockIdx.x >= 3209) {   // weight swizzle: fp32 [k][n] -> B-frag order
        const float* ws[6] = {w0, w1, w2, w3, w4, w5};
        const int wi = blockIdx.x - 3209;
        const float* w = ws[wi];
        unsigned short* o = wfrag + wi * 4096;
        #pragma unroll
        for (int it = 0; it < 2; ++it) {
            const int idx = it * 256 + threadIdx.x;   // fid*64 + lane
            const int fid = idx >> 6, lane = idx & 63;
            const int kt = fid >> 2, nt = fid & 3;
            const int kbase = kt * 32 + (lane >> 4) * 8;
            const int n = nt * 16 + (lane & 15);
            #pragma unroll
            for (int j = 0; j < 8; ++j)
                o[idx * 8 + j] = f2b(w[(kbase + j) * 64 + n]);
        }
        return;
    }
    const int tid = blockIdx.x * 256 + threadIdx.x;
    if (tid < 800000) {
        const float4 v = ((const float4*)x)[tid];
        ushort4 o;
        o.x = f2b(v.x); o.y = f2b(v.y); o.z = f2b(v.z); o.w = f2b(v.w);
        ((ushort4*)xbf)[tid] = o;
    } else if (tid < 812500) {
        ((int4*)counts)[tid - 800000] = make_int4(0, 0, 0, 0);
    } else if (tid < 821460) {
        ((float4*)zblock)[tid - 812500] = make_float4(0.f, 0.f, 0.f, 0.f);
    }
}

// ===========================================================================
// CSR build: histogram -> 2-level exclusive scan -> XCD-partitioned fill.
// ===========================================================================
__global__ __launch_bounds__(256) void hist_kernel(const int* __restrict__ ei,
                                                   int* __restrict__ counts) {
    const int e = blockIdx.x * blockDim.x + threadIdx.x;
    if (e < EE) atomicAdd(&counts[ei[EE + e]], 1);
}

__global__ __launch_bounds__(512) void scan1_kernel(const int* __restrict__ counts,
                                                    int* __restrict__ scanned,
                                                    int* __restrict__ bsum) {
    __shared__ int buf[512];
    const int i = blockIdx.x * 512 + threadIdx.x;
    const int v = (i < NN) ? counts[i] : 0;
    buf[threadIdx.x] = v;
    __syncthreads();
    for (int off = 1; off < 512; off <<= 1) {
        const int add = (threadIdx.x >= off) ? buf[threadIdx.x - off] : 0;
        __syncthreads();
        buf[threadIdx.x] += add;
        __syncthreads();
    }
    if (i < NN) scanned[i] = buf[threadIdx.x] - v;   // exclusive
    if (threadIdx.x == 511) bsum[blockIdx.x] = buf[511];
}

__global__ __launch_bounds__(512) void scan2_kernel(const int* __restrict__ scanned,
                                                    const int* __restrict__ bsum,
                                                    int* __restrict__ rowptr,
                                                    int* __restrict__ cursor) {
    __shared__ int red[128];
    if (threadIdx.x < 128)
        red[threadIdx.x] = (threadIdx.x < blockIdx.x) ? bsum[threadIdx.x] : 0;
    __syncthreads();
    for (int off = 64; off > 0; off >>= 1) {
        if (threadIdx.x < off) red[threadIdx.x] += red[threadIdx.x + off];
        __syncthreads();
    }
    const int offset = red[0];
    const int i = blockIdx.x * 512 + threadIdx.x;
    if (i < NN) {
        const int p = scanned[i] + offset;
        rowptr[i] = p;
        cursor[i] = p;
    }
    if (blockIdx.x == 0 && threadIdx.x == 0) rowptr[NN] = EE;
}

// XCD-class partitioned fill (round-8 fix for 52MB partial-line writebacks).
__global__ __launch_bounds__(256) void fill_kernel(const int* __restrict__ ei,
                                                   int* __restrict__ cursor,
                                                   int* __restrict__ col) {
    const int cls = blockIdx.x & 7;
    const int chunk = blockIdx.x >> 3;              // 0..255
    const int e0 = chunk * 3125;                    // 256*3125 == EE
    for (int e = e0 + threadIdx.x; e < e0 + 3125; e += 256) {
        const int dst = ei[EE + e];
        if (dst / 6250 == cls) {
            const int pos = atomicAdd(&cursor[dst], 1);
            col[pos] = ei[e];
        }
    }
}

// ===========================================================================
// FUSED gather + MFMA MLP. 64-row block, 4 waves; wave owns 16 rows.
// Gather happens directly in MFMA A-fragment layout (row = lane&15, feats
// quad*8+j and 32+quad*8+j): per neighbor-step, ONE per-lane col load + TWO
// 1KB wave-wide h-row loads fetch 16 neighbors' 128B rows (6x fewer VMEM
// issues than 1-wave-per-row gather). fp32 accumulate; prev-layer BN affine;
// in-register bf16 A-frags -> 2 MFMAs per output tile; LDS transpose between
// matmuls; BN stats; bf16 writeback. No z round-trip.
// NN == 781*64 + 16 -> every 16-row strip is fully valid or fully OOB.
// ===========================================================================
__global__ __launch_bounds__(256, 2) void fmlp_kernel(const unsigned short* __restrict__ hin,
                                                      const int* __restrict__ rowptr,
                                                      const int* __restrict__ col,
                                                      const float* __restrict__ ss,
                                                      const int apply,
                                                      const unsigned short* __restrict__ wfa,
                                                      const float* __restrict__ ba,
                                                      const unsigned short* __restrict__ wfb,
                                                      const float* __restrict__ bb,
                                                      unsigned short* __restrict__ tout,
                                                      float* __restrict__ stats) {
    __shared__ unsigned short ldsT[4][16][72];   // per-wave transpose tiles
    __shared__ float red[512];

    const int wave = threadIdx.x >> 6;
    const int lane = threadIdx.x & 63;
    const int quad = lane >> 4;
    const int l15 = lane & 15;
    const int rowbase = blockIdx.x * 64 + wave * 16;
    const bool wvalid = rowbase < NN;            // strip-level validity
    const int row = rowbase + l15;
    const int rp = (row < NN) ? row : (NN - 1);
    const int beg = rowptr[rp];
    const int deg = (row < NN) ? (rowptr[rp + 1] - beg) : 0;

    // ---- gather in A-frag layout: facc[0..7] = feats quad*8+j,
    //      facc[8..15] = feats 32+quad*8+j of this lane's row ----
    float facc[16];
    {
        const short8 h0 = *(const short8*)(hin + rp * 64 + quad * 8);
        const short8 h1 = *(const short8*)(hin + rp * 64 + 32 + quad * 8);
        const float ms = (row < NN) ? 1.f : 0.f;
        #pragma unroll
        for (int j = 0; j < 8; ++j) {
            facc[j]     = b2f((unsigned short)h0[j]) * ms;
            facc[8 + j] = b2f((unsigned short)h1[j]) * ms;
        }
    }
    int md = deg;
    #pragma unroll
    for (int off = 32; off; off >>= 1) md = max(md, __shfl_xor(md, off));
    for (int i = 0; i < md; i += 2) {
        const int j0 = (i < deg) ? (beg + i) : 0;
        const int j1 = (i + 1 < deg) ? (beg + i + 1) : 0;
        const int s0 = col[j0];
        const int s1 = col[j1];
        const short8 p0 = *(const short8*)(hin + s0 * 64 + quad * 8);
        const short8 p1 = *(const short8*)(hin + s0 * 64 + 32 + quad * 8);
        const short8 q0 = *(const short8*)(hin + s1 * 64 + quad * 8);
        const short8 q1 = *(const short8*)(hin + s1 * 64 + 32 + quad * 8);
        const float m0 = (i < deg) ? 1.f : 0.f;
        const float m1 = (i + 1 < deg) ? 1.f : 0.f;
        #pragma unroll
        for (int j = 0; j < 8; ++j) {
            facc[j]     += b2f((unsigned short)p0[j]) * m0;
            facc[j]     += b2f((unsigned short)q0[j]) * m1;
            facc[8 + j] += b2f((unsigned short)p1[j]) * m0;
            facc[8 + j] += b2f((unsigned short)q1[j]) * m1;
        }
    }

    // ---- prev-layer BN affine (per-feature), then bf16 A-frags ----
    short8 a0, a1;
    {
        const float degp1 = (float)(deg + 1);
        #pragma unroll
        for (int j = 0; j < 8; ++j) {
            const float sc0 = apply ? ss[quad * 8 + j] : 1.f;
            const float sf0 = apply ? ss[64 + quad * 8 + j] : 0.f;
            const float sc1 = apply ? ss[32 + quad * 8 + j] : 1.f;
            const float sf1 = apply ? ss[96 + quad * 8 + j] : 0.f;
            a0[j] = (short)f2b(fmaf(facc[j], sc0, degp1 * sf0));
            a1[j] = (short)f2b(fmaf(facc[8 + j], sc1, degp1 * sf1));
        }
    }

    // ---- weight fragments (loaded after gather to limit pressure) ----
    short8 wA[8], wB[8];
    #pragma unroll
    for (int f = 0; f < 8; ++f) {
        wA[f] = *(const short8*)(wfa + (f * 64 + lane) * 8);
        wB[f] = *(const short8*)(wfb + (f * 64 + lane) * 8);
    }
    float biasA[4], biasB[4];
    #pragma unroll
    for (int nt = 0; nt < 4; ++nt) {
        biasA[nt] = ba[nt * 16 + l15];
        biasB[nt] = bb[nt * 16 + l15];
    }

    // ---- matmul 1 ----
    f32x4 acc[4];
    #pragma unroll
    for (int nt = 0; nt < 4; ++nt) {
        f32x4 c = {0.f, 0.f, 0.f, 0.f};
        c = __builtin_amdgcn_mfma_f32_16x16x32_bf16(a0, wA[nt], c, 0, 0, 0);
        c = __builtin_amdgcn_mfma_f32_16x16x32_bf16(a1, wA[4 + nt], c, 0, 0, 0);
        acc[nt] = c;
    }
    #pragma unroll
    for (int nt = 0; nt < 4; ++nt)
        #pragma unroll
        for (int r = 0; r < 4; ++r)
            ldsT[wave][quad * 4 + r][nt * 16 + l15] =
                f2b(fmaxf(acc[nt][r] + biasA[nt], 0.f));

    const short8 y0 = *(const short8*)(&ldsT[wave][l15][quad * 8]);
    const short8 y1 = *(const short8*)(&ldsT[wave][l15][32 + quad * 8]);

    // ---- matmul 2 ----
    #pragma unroll
    for (int nt = 0; nt < 4; ++nt) {
        f32x4 c = {0.f, 0.f, 0.f, 0.f};
        c = __builtin_amdgcn_mfma_f32_16x16x32_bf16(y0, wB[nt], c, 0, 0, 0);
        c = __builtin_amdgcn_mfma_f32_16x16x32_bf16(y1, wB[4 + nt], c, 0, 0, 0);
        acc[nt] = c;
    }
    #pragma unroll
    for (int nt = 0; nt < 4; ++nt)
        #pragma unroll
        for (int r = 0; r < 4; ++r)
            ldsT[wave][quad * 4 + r][nt * 16 + l15] =
                f2b(fmaxf(acc[nt][r] + biasB[nt], 0.f));

    // ---- BN partials (wave reads its own region; same-wave ordered) ----
    {
        float s = 0.f, sq = 0.f;
        if (wvalid) {
            #pragma unroll 4
            for (int r = 0; r < 16; ++r) {
                const float v = b2f(ldsT[wave][r][lane]);
                s += v;
                sq += v * v;
            }
        }
        red[wave * 128 + lane] = s;
        red[wave * 128 + 64 + lane] = sq;
    }
    __syncthreads();

    if (threadIdx.x < 128) {
        const float tot = red[threadIdx.x] + red[128 + threadIdx.x] +
                          red[256 + threadIdx.x] + red[384 + threadIdx.x];
        atomicAdd(&stats[(blockIdx.x & 7) * 128 + threadIdx.x], tot);
    }

    // ---- bf16 writeback (coalesced ushort4) ----
    #pragma unroll
    for (int m = 0; m < 4; ++m) {
        const int g = m * 256 + threadIdx.x;     // 1024 groups of 4 feats
        const int r = g >> 4;
        const int f4 = (g & 15) * 4;
        const int grow = blockIdx.x * 64 + r;
        if (grow < NN)
            *(ushort4*)(tout + grow * 64 + f4) =
                *(const ushort4*)(&ldsT[r >> 4][r & 15][f4]);
    }
}

// ===========================================================================
// stats[8][128] -> fused BN scale/shift (tiny)
// ===========================================================================
__global__ __launch_bounds__(128) void finalize_kernel(const float* __restrict__ stats,
                                                       const float* __restrict__ g,
                                                       const float* __restrict__ be,
                                                       float* __restrict__ ss) {
    __shared__ float red[128];
    const int f = threadIdx.x;
    float tot = 0.f;
    #pragma unroll
    for (int k = 0; k < 8; ++k) tot += stats[k * 128 + f];
    red[f] = tot;
    __syncthreads();
    if (f < 64) {
        const float mean = red[f] * (1.0f / NN);
        const float var = red[64 + f] * (1.0f / NN) - mean * mean;
        const float scl = g[f] * rsqrtf(var + 1e-5f);
        ss[f] = scl;
        ss[64 + f] = be[f] - mean * scl;
    }
}

// ===========================================================================
// Pool (bf16 t in, layer-3 BN finalize folded into preamble); batch sorted.
// ===========================================================================
__global__ __launch_bounds__(256) void pool_kernel(const unsigned short* __restrict__ t,
                                                   const int* __restrict__ batch,
                                                   const float* __restrict__ stats,
                                                   const float* __restrict__ ga,
                                                   const float* __restrict__ be,
                                                   float* __restrict__ xpool) {
    const int wv = (blockIdx.x * 256 + threadIdx.x) >> 6;
    const int lane = threadIdx.x & 63;

    float s = 0.f, sq = 0.f;
    #pragma unroll
    for (int k = 0; k < 8; ++k) {
        s += stats[k * 128 + lane];
        sq += stats[k * 128 + 64 + lane];
    }
    const float mean = s * (1.0f / NN);
    const float var = sq * (1.0f / NN) - mean * mean;
    const float scl = ga[lane] * rsqrtf(var + 1e-5f);
    const float sft = be[lane] - mean * scl;

    const int r0 = wv * 64;
    if (r0 >= NN) return;
    const int r1 = min(r0 + 64, NN);
    int gprev = batch[r0];
    float acc = 0.f;
    for (int r = r0; r < r1; ++r) {
        const int g = batch[r];
        if (g != gprev) {
            __hip_atomic_fetch_add(&xpool[gprev * 64 + lane], acc,
                                   __ATOMIC_RELAXED, __HIP_MEMORY_SCOPE_AGENT);
            acc = 0.f;
            gprev = g;
        }
        acc += fmaf(b2f(t[r * 64 + lane]), scl, sft);
    }
    __hip_atomic_fetch_add(&xpool[gprev * 64 + lane], acc,
                           __ATOMIC_RELAXED, __HIP_MEMORY_SCOPE_AGENT);
}

// ===========================================================================
// Fused head: out[g] = relu((xpool[g] @ w0 + b0) @ w1 + b1). One block per g.
// ===========================================================================
__global__ __launch_bounds__(128) void head_kernel(const float* __restrict__ xpool,
                                                   const float* __restrict__ w0,
                                                   const float* __restrict__ b0,
                                                   const float* __restrict__ w1,
                                                   const float* __restrict__ b1,
                                                   float* __restrict__ out) {
    __shared__ float xp[64];
    __shared__ float midl[128];
    const int g = blockIdx.x;
    const int t = threadIdx.x;
    if (t < 64) xp[t] = xpool[g * 64 + t];
    __syncthreads();
    float acc = b0[t];
    #pragma unroll 8
    for (int k = 0; k < 64; ++k) acc = fmaf(xp[k], w0[k * 128 + t], acc);
    midl[t] = acc;
    __syncthreads();
    if (t < 64) {
        float a2 = b1[t];
        #pragma unroll 8
        for (int k = 0; k < 128; ++k) a2 = fmaf(midl[k], w1[k * 64 + t], a2);
        out[g * 64 + t] = fmaxf(a2, 0.f);
    }
}

extern "C" void kernel_launch(void* const* d_in, const int* in_sizes, int n_in,
                              void* d_out, int out_size, void* d_ws, size_t ws_size,
                              hipStream_t stream) {
    const float* x = (const float*)d_in[0];
    const int* ei = (const int*)d_in[1];
    const int* batch = (const int*)d_in[2];

    // ---- workspace layout ----
    int* ibase   = (int*)d_ws;
    int* counts  = ibase;            // 50000 (int4-zeroable)
    int* scanned = ibase + 50000;    // 50000
    int* rowptr  = ibase + 100000;   // 50001 (pad to 50004)
    int* cursor  = ibase + 150004;   // 50000
    int* bsum    = ibase + 200004;   // 128 (98 used)
    int* col     = ibase + 200132;   // 800000 -> int end 1,000,132 (pad 1,000,192)
    float* fbase = (float*)d_ws + 1000192;       // 16B aligned
    float* stats = fbase;                        // 3 x 1024 = 3072
    float* xpool = stats + 3072;                 // 32768 (zeroed by prep)
    float* ss    = fbase + 35840;                // 128
    unsigned short* xbf  = (unsigned short*)(fbase + 36096);  // NN*64 bf16
    unsigned short* t0bf = xbf + 3200000;
    unsigned short* t1bf = t0bf + 3200000;
    unsigned short* wfrag = t1bf + 3200000;      // 6 x 4096 bf16

    // ---- prep (x->bf16 + zeroing + weight swizzle) + CSR build ----
    prep_kernel<<<3215, 256, 0, stream>>>(x, xbf, counts, stats,
                                          (const float*)d_in[3], (const float*)d_in[5],
                                          (const float*)d_in[9], (const float*)d_in[11],
                                          (const float*)d_in[15], (const float*)d_in[17],
                                          wfrag);
    hist_kernel<<<(EE + 255) / 256, 256, 0, stream>>>(ei, counts);
    scan1_kernel<<<SCAN_BLOCKS, 512, 0, stream>>>(counts, scanned, bsum);
    scan2_kernel<<<SCAN_BLOCKS, 512, 0, stream>>>(scanned, bsum, rowptr, cursor);
    fill_kernel<<<2048, 256, 0, stream>>>(ei, cursor, col);

    // ---- 3 fused GIN layers (gather+MFMA mlp in one kernel) ----
    const unsigned short* hcur = xbf;
    unsigned short* touts[3] = {t0bf, t1bf, t0bf};
    for (int l = 0; l < 3; ++l) {
        const float* ba = (const float*)d_in[3 + l * 6 + 1];
        const float* bb = (const float*)d_in[3 + l * 6 + 3];
        const float* ga = (const float*)d_in[3 + l * 6 + 4];
        const float* be = (const float*)d_in[3 + l * 6 + 5];

        fmlp_kernel<<<TILES, 256, 0, stream>>>(hcur, rowptr, col, ss, l > 0,
                                               wfrag + (l * 2 + 0) * 4096, ba,
                                               wfrag + (l * 2 + 1) * 4096, bb,
                                               touts[l], stats + l * 1024);
        if (l < 2)   // layer-3 finalize is folded into pool
            finalize_kernel<<<1, 128, 0, stream>>>(stats + l * 1024, ga, be, ss);
        hcur = touts[l];
    }

    pool_kernel<<<(TILES + 3) / 4, 256, 0, stream>>>(
        t0bf, batch, stats + 2048,
        (const float*)d_in[19], (const float*)d_in[20], xpool);
    head_kernel<<<GG, 128, 0, stream>>>(
        xpool, (const float*)d_in[21], (const float*)d_in[22],
        (const float*)d_in[23], (const float*)d_in[24], (float*)d_out);
}

// Round 15
// 316.072 us; speedup vs baseline: 1.0032x; 1.0032x over previous
//
#include <hip/hip_runtime.h>

#define NN 50000
#define EE 800000
#define DD 64
#define GG 512
#define TILES 782          // ceil(NN/64)
#define SCAN_BLOCKS 98     // ceil(NN/512)

typedef __attribute__((ext_vector_type(8))) short short8;
typedef __attribute__((ext_vector_type(4))) float f32x4;

// ---- bf16 helpers ----
__device__ __forceinline__ float b2f(unsigned short u) {
    union { unsigned int i; float f; } c;
    c.i = ((unsigned int)u) << 16;
    return c.f;
}
__device__ __forceinline__ unsigned short f2b(float f) {
    union { float f; unsigned int i; } c;
    c.f = f;
    const unsigned int r = c.i + 0x7FFFu + ((c.i >> 16) & 1u);  // rne
    return (unsigned short)(r >> 16);
}
__device__ __forceinline__ int rfl(int v) { return __builtin_amdgcn_readfirstlane(v); }

// ===========================================================================
// prep: x fp32 -> bf16 + all zeroing (counts, stats, xpool) + weight swizzle
// (last 6 blocks).
// ===========================================================================
__global__ __launch_bounds__(256) void prep_kernel(const float* __restrict__ x,
                                                   unsigned short* __restrict__ xbf,
                                                   int* __restrict__ counts,
                                                   float* __restrict__ zblock,
                                                   const float* __restrict__ w0,
                                                   const float* __restrict__ w1,
                                                   const float* __restrict__ w2,
                                                   const float* __restrict__ w3,
                                                   const float* __restrict__ w4,
                                                   const float* __restrict__ w5,
                                                   unsigned short* __restrict__ wfrag) {
    if (blockIdx.x >= 3209) {   // weight swizzle: fp32 [k][n] -> B-frag order
        const float* ws[6] = {w0, w1, w2, w3, w4, w5};
        const int wi = blockIdx.x - 3209;
        const float* w = ws[wi];
        unsigned short* o = wfrag + wi * 4096;
        #pragma unroll
        for (int it = 0; it < 2; ++it) {
            const int idx = it * 256 + threadIdx.x;   // fid*64 + lane
            const int fid = idx >> 6, lane = idx & 63;
            const int kt = fid >> 2, nt = fid & 3;
            const int kbase = kt * 32 + (lane >> 4) * 8;
            const int n = nt * 16 + (lane & 15);
            #pragma unroll
            for (int j = 0; j < 8; ++j)
                o[idx * 8 + j] = f2b(w[(kbase + j) * 64 + n]);
        }
        return;
    }
    const int tid = blockIdx.x * 256 + threadIdx.x;
    if (tid < 800000) {
        const float4 v = ((const float4*)x)[tid];
        ushort4 o;
        o.x = f2b(v.x); o.y = f2b(v.y); o.z = f2b(v.z); o.w = f2b(v.w);
        ((ushort4*)xbf)[tid] = o;
    } else if (tid < 812500) {
        ((int4*)counts)[tid - 800000] = make_int4(0, 0, 0, 0);
    } else if (tid < 821460) {
        ((float4*)zblock)[tid - 812500] = make_float4(0.f, 0.f, 0.f, 0.f);
    }
}

// ===========================================================================
// CSR build: histogram -> 2-level exclusive scan -> XCD-partitioned fill.
// ===========================================================================
__global__ __launch_bounds__(256) void hist_kernel(const int* __restrict__ ei,
                                                   int* __restrict__ counts) {
    const int e = blockIdx.x * blockDim.x + threadIdx.x;
    if (e < EE) atomicAdd(&counts[ei[EE + e]], 1);
}

__global__ __launch_bounds__(512) void scan1_kernel(const int* __restrict__ counts,
                                                    int* __restrict__ scanned,
                                                    int* __restrict__ bsum) {
    __shared__ int buf[512];
    const int i = blockIdx.x * 512 + threadIdx.x;
    const int v = (i < NN) ? counts[i] : 0;
    buf[threadIdx.x] = v;
    __syncthreads();
    for (int off = 1; off < 512; off <<= 1) {
        const int add = (threadIdx.x >= off) ? buf[threadIdx.x - off] : 0;
        __syncthreads();
        buf[threadIdx.x] += add;
        __syncthreads();
    }
    if (i < NN) scanned[i] = buf[threadIdx.x] - v;   // exclusive
    if (threadIdx.x == 511) bsum[blockIdx.x] = buf[511];
}

__global__ __launch_bounds__(512) void scan2_kernel(const int* __restrict__ scanned,
                                                    const int* __restrict__ bsum,
                                                    int* __restrict__ rowptr,
                                                    int* __restrict__ cursor) {
    __shared__ int red[128];
    if (threadIdx.x < 128)
        red[threadIdx.x] = (threadIdx.x < blockIdx.x) ? bsum[threadIdx.x] : 0;
    __syncthreads();
    for (int off = 64; off > 0; off >>= 1) {
        if (threadIdx.x < off) red[threadIdx.x] += red[threadIdx.x + off];
        __syncthreads();
    }
    const int offset = red[0];
    const int i = blockIdx.x * 512 + threadIdx.x;
    if (i < NN) {
        const int p = scanned[i] + offset;
        rowptr[i] = p;
        cursor[i] = p;
    }
    if (blockIdx.x == 0 && threadIdx.x == 0) rowptr[NN] = EE;
}

// Class-partitioned fill, 16 classes (round-15: smaller 400KB regions for
// better write-line residency; dst array is L2-hot after the first pass).
__global__ __launch_bounds__(256) void fill_kernel(const int* __restrict__ ei,
                                                   int* __restrict__ cursor,
                                                   int* __restrict__ col) {
    const int cls = blockIdx.x & 15;
    const int chunk = blockIdx.x >> 4;              // 0..255
    const int e0 = chunk * 3125;                    // 256*3125 == EE
    for (int e = e0 + threadIdx.x; e < e0 + 3125; e += 256) {
        const int dst = ei[EE + e];
        if (dst / 3125 == cls) {
            const int pos = atomicAdd(&cursor[dst], 1);
            col[pos] = ei[e];
        }
    }
}

// ===========================================================================
// Gather: one wave per row (50000 waves), deg-adaptive single-drain batches
// (16/24/32/loop). Previous layer's BN finalize folded into the preamble.
// Writes z as bf16. z = scl.*(h_self + sum_nbr h) + (deg+1).*sft
// ===========================================================================
__global__ __launch_bounds__(256, 4) void gather_kernel(const unsigned short* __restrict__ hin,
                                                        const int* __restrict__ rowptr,
                                                        const int* __restrict__ col,
                                                        const float* __restrict__ stats,
                                                        const float* __restrict__ ga,
                                                        const float* __restrict__ be,
                                                        const int apply,
                                                        unsigned short* __restrict__ z) {
    const int wv = (blockIdx.x * 256 + threadIdx.x) >> 6;
    const int lane = threadIdx.x & 63;
    const int row = rfl(wv);
    if (row >= NN) return;

    float scl = 1.0f, sft = 0.0f;
    if (apply) {   // folded finalize (1KB stats region, L2-hot)
        float s = 0.f, sq = 0.f;
        #pragma unroll
        for (int k = 0; k < 8; ++k) {
            s += stats[k * 128 + lane];
            sq += stats[k * 128 + 64 + lane];
        }
        const float mean = s * (1.0f / NN);
        const float var = sq * (1.0f / NN) - mean * mean;
        scl = ga[lane] * rsqrtf(var + 1e-5f);
        sft = be[lane] - mean * scl;
    }

    const int beg = rfl(rowptr[row]);
    const int end = rfl(rowptr[row + 1]);
    const int deg = end - beg;
    float a[8];
    #pragma unroll
    for (int i = 0; i < 8; ++i) a[i] = 0.f;
    a[0] = b2f(hin[row * 64 + lane]);   // self term

    if (deg <= 16) {
        const int safeb = (beg < EE) ? beg : 0;
        int c[16];
        #pragma unroll
        for (int i = 0; i < 16; ++i) {
            const int jj = (i < deg) ? (beg + i) : safeb;
            c[i] = rfl(col[jj]);
        }
        float hv[16];
        #pragma unroll
        for (int i = 0; i < 16; ++i) hv[i] = b2f(hin[c[i] * 64 + lane]);
        #pragma unroll
        for (int i = 0; i < 16; ++i) a[i & 7] += (i < deg) ? hv[i] : 0.f;
    } else if (deg <= 24) {
        int c[24];
        #pragma unroll
        for (int i = 0; i < 24; ++i) {
            const int jj = (i < deg) ? (beg + i) : beg;
            c[i] = rfl(col[jj]);
        }
        float hv[24];
        #pragma unroll
        for (int i = 0; i < 24; ++i) hv[i] = b2f(hin[c[i] * 64 + lane]);
        #pragma unroll
        for (int i = 0; i < 24; ++i) a[i & 7] += (i < deg) ? hv[i] : 0.f;
    } else if (deg <= 32) {
        int c[32];
        #pragma unroll
        for (int i = 0; i < 32; ++i) {
            const int jj = (i < deg) ? (beg + i) : beg;
            c[i] = rfl(col[jj]);
        }
        float hv[32];
        #pragma unroll
        for (int i = 0; i < 32; ++i) hv[i] = b2f(hin[c[i] * 64 + lane]);
        #pragma unroll
        for (int i = 0; i < 32; ++i) a[i & 7] += (i < deg) ? hv[i] : 0.f;
    } else {
        int j = beg;
        for (; j + 16 <= end; j += 16) {
            int c[16];
            #pragma unroll
            for (int i = 0; i < 16; ++i) c[i] = rfl(col[j + i]);
            float hv[16];
            #pragma unroll
            for (int i = 0; i < 16; ++i) hv[i] = b2f(hin[c[i] * 64 + lane]);
            #pragma unroll
            for (int i = 0; i < 16; ++i) a[i & 7] += hv[i];
        }
        if (j < end) {
            int c[16];
            #pragma unroll
            for (int i = 0; i < 16; ++i) {
                const int jj = (j + i < end) ? (j + i) : beg;
                c[i] = rfl(col[jj]);
            }
            float hv[16];
            #pragma unroll
            for (int i = 0; i < 16; ++i) hv[i] = b2f(hin[c[i] * 64 + lane]);
            #pragma unroll
            for (int i = 0; i < 16; ++i) a[i & 7] += (j + i < end) ? hv[i] : 0.f;
        }
    }
    const float sum = ((a[0] + a[1]) + (a[2] + a[3])) + ((a[4] + a[5]) + (a[6] + a[7]));
    z[row * 64 + lane] = f2b(fmaf(sum, scl, (float)(deg + 1) * sft));
}

// ===========================================================================
// MFMA MLP: 64-row block, 4 waves; wave computes its 16x64 strip with
// mfma_f32_16x16x32_bf16. launch_bounds(256,2) keeps wA/wB register-resident.
// No fences/tickets (round-11 lesson).
// ===========================================================================
__global__ __launch_bounds__(256, 2) void mlp_kernel(const unsigned short* __restrict__ z,
                                                     const unsigned short* __restrict__ wfa,
                                                     const float* __restrict__ ba,
                                                     const unsigned short* __restrict__ wfb,
                                                     const float* __restrict__ bb,
                                                     unsigned short* __restrict__ tout,
                                                     float* __restrict__ stats) {
    __shared__ unsigned short ldsT[4][16][72];   // per-wave transpose tiles
    __shared__ float red[512];

    const int wave = threadIdx.x >> 6;
    const int lane = threadIdx.x & 63;
    const int quad = lane >> 4;
    const int l15 = lane & 15;
    const int rowbase = blockIdx.x * 64 + wave * 16;
    const bool valid = rowbase < NN;

    short8 wA[8], wB[8];
    #pragma unroll
    for (int f = 0; f < 8; ++f) {
        wA[f] = *(const short8*)(wfa + (f * 64 + lane) * 8);
        wB[f] = *(const short8*)(wfb + (f * 64 + lane) * 8);
    }
    float biasA[4], biasB[4];
    #pragma unroll
    for (int nt = 0; nt < 4; ++nt) {
        biasA[nt] = ba[nt * 16 + l15];
        biasB[nt] = bb[nt * 16 + l15];
    }

    const int arow = valid ? (rowbase + l15) : 0;
    const short8 a0 = *(const short8*)(z + arow * 64 + quad * 8);
    const short8 a1 = *(const short8*)(z + arow * 64 + 32 + quad * 8);

    f32x4 acc[4];
    #pragma unroll
    for (int nt = 0; nt < 4; ++nt) {
        f32x4 c = {0.f, 0.f, 0.f, 0.f};
        c = __builtin_amdgcn_mfma_f32_16x16x32_bf16(a0, wA[nt], c, 0, 0, 0);
        c = __builtin_amdgcn_mfma_f32_16x16x32_bf16(a1, wA[4 + nt], c, 0, 0, 0);
        acc[nt] = c;
    }
    #pragma unroll
    for (int nt = 0; nt < 4; ++nt)
        #pragma unroll
        for (int r = 0; r < 4; ++r)
            ldsT[wave][quad * 4 + r][nt * 16 + l15] =
                f2b(fmaxf(acc[nt][r] + biasA[nt], 0.f));

    const short8 y0 = *(const short8*)(&ldsT[wave][l15][quad * 8]);
    const short8 y1 = *(const short8*)(&ldsT[wave][l15][32 + quad * 8]);

    #pragma unroll
    for (int nt = 0; nt < 4; ++nt) {
        f32x4 c = {0.f, 0.f, 0.f, 0.f};
        c = __builtin_amdgcn_mfma_f32_16x16x32_bf16(y0, wB[nt], c, 0, 0, 0);
        c = __builtin_amdgcn_mfma_f32_16x16x32_bf16(y1, wB[4 + nt], c, 0, 0, 0);
        acc[nt] = c;
    }
    #pragma unroll
    for (int nt = 0; nt < 4; ++nt)
        #pragma unroll
        for (int r = 0; r < 4; ++r)
            ldsT[wave][quad * 4 + r][nt * 16 + l15] =
                f2b(fmaxf(acc[nt][r] + biasB[nt], 0.f));

    // BN partials (wave reads its own region; same-wave ordered)
    {
        float s = 0.f, sq = 0.f;
        if (valid) {
            #pragma unroll 4
            for (int r = 0; r < 16; ++r) {
                const float v = b2f(ldsT[wave][r][lane]);
                s += v;
                sq += v * v;
            }
        }
        red[wave * 128 + lane] = s;
        red[wave * 128 + 64 + lane] = sq;
    }
    __syncthreads();

    if (threadIdx.x < 128) {
        const float tot = red[threadIdx.x] + red[128 + threadIdx.x] +
                          red[256 + threadIdx.x] + red[384 + threadIdx.x];
        atomicAdd(&stats[(blockIdx.x & 7) * 128 + threadIdx.x], tot);
    }

    #pragma unroll
    for (int m = 0; m < 4; ++m) {
        const int g = m * 256 + threadIdx.x;     // 1024 groups of 4 feats
        const int r = g >> 4;
        const int f4 = (g & 15) * 4;
        const int grow = blockIdx.x * 64 + r;
        if (grow < NN)
            *(ushort4*)(tout + grow * 64 + f4) =
                *(const ushort4*)(&ldsT[r >> 4][r & 15][f4]);
    }
}

// ===========================================================================
// Pool (bf16 t in, layer-3 BN finalize folded into preamble); batch sorted.
// ===========================================================================
__global__ __launch_bounds__(256) void pool_kernel(const unsigned short* __restrict__ t,
                                                   const int* __restrict__ batch,
                                                   const float* __restrict__ stats,
                                                   const float* __restrict__ ga,
                                                   const float* __restrict__ be,
                                                   float* __restrict__ xpool) {
    const int wv = (blockIdx.x * 256 + threadIdx.x) >> 6;
    const int lane = threadIdx.x & 63;

    float s = 0.f, sq = 0.f;
    #pragma unroll
    for (int k = 0; k < 8; ++k) {
        s += stats[k * 128 + lane];
        sq += stats[k * 128 + 64 + lane];
    }
    const float mean = s * (1.0f / NN);
    const float var = sq * (1.0f / NN) - mean * mean;
    const float scl = ga[lane] * rsqrtf(var + 1e-5f);
    const float sft = be[lane] - mean * scl;

    const int r0 = wv * 64;
    if (r0 >= NN) return;
    const int r1 = min(r0 + 64, NN);
    int gprev = batch[r0];
    float acc = 0.f;
    for (int r = r0; r < r1; ++r) {
        const int g = batch[r];
        if (g != gprev) {
            __hip_atomic_fetch_add(&xpool[gprev * 64 + lane], acc,
                                   __ATOMIC_RELAXED, __HIP_MEMORY_SCOPE_AGENT);
            acc = 0.f;
            gprev = g;
        }
        acc += fmaf(b2f(t[r * 64 + lane]), scl, sft);
    }
    __hip_atomic_fetch_add(&xpool[gprev * 64 + lane], acc,
                           __ATOMIC_RELAXED, __HIP_MEMORY_SCOPE_AGENT);
}

// ===========================================================================
// Fused head: out[g] = relu((xpool[g] @ w0 + b0) @ w1 + b1). One block per g.
// ===========================================================================
__global__ __launch_bounds__(128) void head_kernel(const float* __restrict__ xpool,
                                                   const float* __restrict__ w0,
                                                   const float* __restrict__ b0,
                                                   const float* __restrict__ w1,
                                                   const float* __restrict__ b1,
                                                   float* __restrict__ out) {
    __shared__ float xp[64];
    __shared__ float midl[128];
    const int g = blockIdx.x;
    const int t = threadIdx.x;
    if (t < 64) xp[t] = xpool[g * 64 + t];
    __syncthreads();
    float acc = b0[t];
    #pragma unroll 8
    for (int k = 0; k < 64; ++k) acc = fmaf(xp[k], w0[k * 128 + t], acc);
    midl[t] = acc;
    __syncthreads();
    if (t < 64) {
        float a2 = b1[t];
        #pragma unroll 8
        for (int k = 0; k < 128; ++k) a2 = fmaf(midl[k], w1[k * 64 + t], a2);
        out[g * 64 + t] = fmaxf(a2, 0.f);
    }
}

extern "C" void kernel_launch(void* const* d_in, const int* in_sizes, int n_in,
                              void* d_out, int out_size, void* d_ws, size_t ws_size,
                              hipStream_t stream) {
    const float* x = (const float*)d_in[0];
    const int* ei = (const int*)d_in[1];
    const int* batch = (const int*)d_in[2];

    // ---- workspace layout ----
    int* ibase   = (int*)d_ws;
    int* counts  = ibase;            // 50000 (int4-zeroable)
    int* scanned = ibase + 50000;    // 50000
    int* rowptr  = ibase + 100000;   // 50001 (pad to 50004)
    int* cursor  = ibase + 150004;   // 50000
    int* bsum    = ibase + 200004;   // 128 (98 used)
    int* col     = ibase + 200132;   // 800000 -> int end 1,000,132 (pad 1,000,192)
    float* fbase = (float*)d_ws + 1000192;       // 16B aligned
    float* stats = fbase;                        // 3 x 1024 = 3072
    float* xpool = stats + 3072;                 // 32768 (zeroed by prep)
    unsigned short* zbf  = (unsigned short*)(fbase + 35856 + 128);  // NN*64
    unsigned short* xbf  = zbf + 3200000;
    unsigned short* t0bf = xbf + 3200000;
    unsigned short* t1bf = t0bf + 3200000;
    unsigned short* wfrag = t1bf + 3200000;      // 6 x 4096 bf16

    // ---- prep (x->bf16 + zeroing + weight swizzle) + CSR build ----
    prep_kernel<<<3215, 256, 0, stream>>>(x, xbf, counts, stats,
                                          (const float*)d_in[3], (const float*)d_in[5],
                                          (const float*)d_in[9], (const float*)d_in[11],
                                          (const float*)d_in[15], (const float*)d_in[17],
                                          wfrag);
    hist_kernel<<<(EE + 255) / 256, 256, 0, stream>>>(ei, counts);
    scan1_kernel<<<SCAN_BLOCKS, 512, 0, stream>>>(counts, scanned, bsum);
    scan2_kernel<<<SCAN_BLOCKS, 512, 0, stream>>>(scanned, bsum, rowptr, cursor);
    fill_kernel<<<4096, 256, 0, stream>>>(ei, cursor, col);

    // ---- 3 GIN layers: gather (folded finalize) + MFMA mlp ----
    const unsigned short* hcur = xbf;
    unsigned short* touts[3] = {t0bf, t1bf, t0bf};
    for (int l = 0; l < 3; ++l) {
        const float* ba = (const float*)d_in[3 + l * 6 + 1];
        const float* bb = (const float*)d_in[3 + l * 6 + 3];
        const float* gp = (const float*)d_in[3 + (l ? (l - 1) : 0) * 6 + 4];
        const float* bp = (const float*)d_in[3 + (l ? (l - 1) : 0) * 6 + 5];

        gather_kernel<<<12500, 256, 0, stream>>>(hcur, rowptr, col,
                                                 stats + (l ? (l - 1) : 0) * 1024,
                                                 gp, bp, l > 0, zbf);
        mlp_kernel<<<TILES, 256, 0, stream>>>(zbf,
                                              wfrag + (l * 2 + 0) * 4096, ba,
                                              wfrag + (l * 2 + 1) * 4096, bb,
                                              touts[l], stats + l * 1024);
        hcur = touts[l];
    }

    pool_kernel<<<(TILES + 3) / 4, 256, 0, stream>>>(
        t0bf, batch, stats + 2048,
        (const float*)d_in[19], (const float*)d_in[20], xpool);
    head_kernel<<<GG, 128, 0, stream>>>(
        xpool, (const float*)d_in[21], (const float*)d_in[22],
        (const float*)d_in[23], (const float*)d_in[24], (float*)d_out);
}

// Round 16
// 313.162 us; speedup vs baseline: 1.0125x; 1.0093x over previous
//
#include <hip/hip_runtime.h>

#define NN 50000
#define EE 800000
#define DD 64
#define GG 512
#define TILES 782          // ceil(NN/64)
#define SCAN_BLOCKS 98     // ceil(NN/512)

typedef __attribute__((ext_vector_type(8))) short short8;
typedef __attribute__((ext_vector_type(4))) float f32x4;

// ---- bf16 helpers ----
__device__ __forceinline__ float b2f(unsigned short u) {
    union { unsigned int i; float f; } c;
    c.i = ((unsigned int)u) << 16;
    return c.f;
}
__device__ __forceinline__ unsigned short f2b(float f) {
    union { float f; unsigned int i; } c;
    c.f = f;
    const unsigned int r = c.i + 0x7FFFu + ((c.i >> 16) & 1u);  // rne
    return (unsigned short)(r >> 16);
}
__device__ __forceinline__ int rfl(int v) { return __builtin_amdgcn_readfirstlane(v); }

// ===========================================================================
// prep: x fp32 -> bf16 + all zeroing (counts, stats, xpool) + weight swizzle
// (last 6 blocks).
// ===========================================================================
__global__ __launch_bounds__(256) void prep_kernel(const float* __restrict__ x,
                                                   unsigned short* __restrict__ xbf,
                                                   int* __restrict__ counts,
                                                   float* __restrict__ zblock,
                                                   const float* __restrict__ w0,
                                                   const float* __restrict__ w1,
                                                   const float* __restrict__ w2,
                                                   const float* __restrict__ w3,
                                                   const float* __restrict__ w4,
                                                   const float* __restrict__ w5,
                                                   unsigned short* __restrict__ wfrag) {
    if (blockIdx.x >= 3209) {   // weight swizzle: fp32 [k][n] -> B-frag order
        const float* ws[6] = {w0, w1, w2, w3, w4, w5};
        const int wi = blockIdx.x - 3209;
        const float* w = ws[wi];
        unsigned short* o = wfrag + wi * 4096;
        #pragma unroll
        for (int it = 0; it < 2; ++it) {
            const int idx = it * 256 + threadIdx.x;   // fid*64 + lane
            const int fid = idx >> 6, lane = idx & 63;
            const int kt = fid >> 2, nt = fid & 3;
            const int kbase = kt * 32 + (lane >> 4) * 8;
            const int n = nt * 16 + (lane & 15);
            #pragma unroll
            for (int j = 0; j < 8; ++j)
                o[idx * 8 + j] = f2b(w[(kbase + j) * 64 + n]);
        }
        return;
    }
    const int tid = blockIdx.x * 256 + threadIdx.x;
    if (tid < 800000) {
        const float4 v = ((const float4*)x)[tid];
        ushort4 o;
        o.x = f2b(v.x); o.y = f2b(v.y); o.z = f2b(v.z); o.w = f2b(v.w);
        ((ushort4*)xbf)[tid] = o;
    } else if (tid < 812500) {
        ((int4*)counts)[tid - 800000] = make_int4(0, 0, 0, 0);
    } else if (tid < 821460) {
        ((float4*)zblock)[tid - 812500] = make_float4(0.f, 0.f, 0.f, 0.f);
    }
}

// ===========================================================================
// CSR build: histogram -> 2-level exclusive scan -> XCD-partitioned fill.
// ===========================================================================
__global__ __launch_bounds__(256) void hist_kernel(const int* __restrict__ ei,
                                                   int* __restrict__ counts) {
    const int e = blockIdx.x * blockDim.x + threadIdx.x;
    if (e < EE) atomicAdd(&counts[ei[EE + e]], 1);
}

__global__ __launch_bounds__(512) void scan1_kernel(const int* __restrict__ counts,
                                                    int* __restrict__ scanned,
                                                    int* __restrict__ bsum) {
    __shared__ int buf[512];
    const int i = blockIdx.x * 512 + threadIdx.x;
    const int v = (i < NN) ? counts[i] : 0;
    buf[threadIdx.x] = v;
    __syncthreads();
    for (int off = 1; off < 512; off <<= 1) {
        const int add = (threadIdx.x >= off) ? buf[threadIdx.x - off] : 0;
        __syncthreads();
        buf[threadIdx.x] += add;
        __syncthreads();
    }
    if (i < NN) scanned[i] = buf[threadIdx.x] - v;   // exclusive
    if (threadIdx.x == 511) bsum[blockIdx.x] = buf[511];
}

__global__ __launch_bounds__(512) void scan2_kernel(const int* __restrict__ scanned,
                                                    const int* __restrict__ bsum,
                                                    int* __restrict__ rowptr,
                                                    int* __restrict__ cursor) {
    __shared__ int red[128];
    if (threadIdx.x < 128)
        red[threadIdx.x] = (threadIdx.x < blockIdx.x) ? bsum[threadIdx.x] : 0;
    __syncthreads();
    for (int off = 64; off > 0; off >>= 1) {
        if (threadIdx.x < off) red[threadIdx.x] += red[threadIdx.x + off];
        __syncthreads();
    }
    const int offset = red[0];
    const int i = blockIdx.x * 512 + threadIdx.x;
    if (i < NN) {
        const int p = scanned[i] + offset;
        rowptr[i] = p;
        cursor[i] = p;
    }
    if (blockIdx.x == 0 && threadIdx.x == 0) rowptr[NN] = EE;
}

// 8-class partitioned fill (round-16: reverted from 16 classes — the extra
// filtered re-reads of ei cost more than the smaller write regions saved;
// 8-class is the empirically best point).
__global__ __launch_bounds__(256) void fill_kernel(const int* __restrict__ ei,
                                                   int* __restrict__ cursor,
                                                   int* __restrict__ col) {
    const int cls = blockIdx.x & 7;
    const int chunk = blockIdx.x >> 3;              // 0..255
    const int e0 = chunk * 3125;                    // 256*3125 == EE
    for (int e = e0 + threadIdx.x; e < e0 + 3125; e += 256) {
        const int dst = ei[EE + e];
        if (dst / 6250 == cls) {
            const int pos = atomicAdd(&cursor[dst], 1);
            col[pos] = ei[e];
        }
    }
}

// ===========================================================================
// Gather: one wave per row (50000 waves), deg-adaptive single-drain batches
// (16/24/32/loop). Previous layer's BN finalize folded into the preamble.
// Writes z as bf16. z = scl.*(h_self + sum_nbr h) + (deg+1).*sft
// ===========================================================================
__global__ __launch_bounds__(256, 4) void gather_kernel(const unsigned short* __restrict__ hin,
                                                        const int* __restrict__ rowptr,
                                                        const int* __restrict__ col,
                                                        const float* __restrict__ stats,
                                                        const float* __restrict__ ga,
                                                        const float* __restrict__ be,
                                                        const int apply,
                                                        unsigned short* __restrict__ z) {
    const int wv = (blockIdx.x * 256 + threadIdx.x) >> 6;
    const int lane = threadIdx.x & 63;
    const int row = rfl(wv);
    if (row >= NN) return;

    float scl = 1.0f, sft = 0.0f;
    if (apply) {   // folded finalize (1KB stats region, L2-hot)
        float s = 0.f, sq = 0.f;
        #pragma unroll
        for (int k = 0; k < 8; ++k) {
            s += stats[k * 128 + lane];
            sq += stats[k * 128 + 64 + lane];
        }
        const float mean = s * (1.0f / NN);
        const float var = sq * (1.0f / NN) - mean * mean;
        scl = ga[lane] * rsqrtf(var + 1e-5f);
        sft = be[lane] - mean * scl;
    }

    const int beg = rfl(rowptr[row]);
    const int end = rfl(rowptr[row + 1]);
    const int deg = end - beg;
    float a[8];
    #pragma unroll
    for (int i = 0; i < 8; ++i) a[i] = 0.f;
    a[0] = b2f(hin[row * 64 + lane]);   // self term

    if (deg <= 16) {
        const int safeb = (beg < EE) ? beg : 0;
        int c[16];
        #pragma unroll
        for (int i = 0; i < 16; ++i) {
            const int jj = (i < deg) ? (beg + i) : safeb;
            c[i] = rfl(col[jj]);
        }
        float hv[16];
        #pragma unroll
        for (int i = 0; i < 16; ++i) hv[i] = b2f(hin[c[i] * 64 + lane]);
        #pragma unroll
        for (int i = 0; i < 16; ++i) a[i & 7] += (i < deg) ? hv[i] : 0.f;
    } else if (deg <= 24) {
        int c[24];
        #pragma unroll
        for (int i = 0; i < 24; ++i) {
            const int jj = (i < deg) ? (beg + i) : beg;
            c[i] = rfl(col[jj]);
        }
        float hv[24];
        #pragma unroll
        for (int i = 0; i < 24; ++i) hv[i] = b2f(hin[c[i] * 64 + lane]);
        #pragma unroll
        for (int i = 0; i < 24; ++i) a[i & 7] += (i < deg) ? hv[i] : 0.f;
    } else if (deg <= 32) {
        int c[32];
        #pragma unroll
        for (int i = 0; i < 32; ++i) {
            const int jj = (i < deg) ? (beg + i) : beg;
            c[i] = rfl(col[jj]);
        }
        float hv[32];
        #pragma unroll
        for (int i = 0; i < 32; ++i) hv[i] = b2f(hin[c[i] * 64 + lane]);
        #pragma unroll
        for (int i = 0; i < 32; ++i) a[i & 7] += (i < deg) ? hv[i] : 0.f;
    } else {
        int j = beg;
        for (; j + 16 <= end; j += 16) {
            int c[16];
            #pragma unroll
            for (int i = 0; i < 16; ++i) c[i] = rfl(col[j + i]);
            float hv[16];
            #pragma unroll
            for (int i = 0; i < 16; ++i) hv[i] = b2f(hin[c[i] * 64 + lane]);
            #pragma unroll
            for (int i = 0; i < 16; ++i) a[i & 7] += hv[i];
        }
        if (j < end) {
            int c[16];
            #pragma unroll
            for (int i = 0; i < 16; ++i) {
                const int jj = (j + i < end) ? (j + i) : beg;
                c[i] = rfl(col[jj]);
            }
            float hv[16];
            #pragma unroll
            for (int i = 0; i < 16; ++i) hv[i] = b2f(hin[c[i] * 64 + lane]);
            #pragma unroll
            for (int i = 0; i < 16; ++i) a[i & 7] += (j + i < end) ? hv[i] : 0.f;
        }
    }
    const float sum = ((a[0] + a[1]) + (a[2] + a[3])) + ((a[4] + a[5]) + (a[6] + a[7]));
    z[row * 64 + lane] = f2b(fmaf(sum, scl, (float)(deg + 1) * sft));
}

// ===========================================================================
// MFMA MLP: 64-row block, 4 waves; wave computes its 16x64 strip with
// mfma_f32_16x16x32_bf16. launch_bounds(256,2) keeps wA/wB register-resident.
// No fences/tickets (round-11 lesson).
// ===========================================================================
__global__ __launch_bounds__(256, 2) void mlp_kernel(const unsigned short* __restrict__ z,
                                                     const unsigned short* __restrict__ wfa,
                                                     const float* __restrict__ ba,
                                                     const unsigned short* __restrict__ wfb,
                                                     const float* __restrict__ bb,
                                                     unsigned short* __restrict__ tout,
                                                     float* __restrict__ stats) {
    __shared__ unsigned short ldsT[4][16][72];   // per-wave transpose tiles
    __shared__ float red[512];

    const int wave = threadIdx.x >> 6;
    const int lane = threadIdx.x & 63;
    const int quad = lane >> 4;
    const int l15 = lane & 15;
    const int rowbase = blockIdx.x * 64 + wave * 16;
    const bool valid = rowbase < NN;

    short8 wA[8], wB[8];
    #pragma unroll
    for (int f = 0; f < 8; ++f) {
        wA[f] = *(const short8*)(wfa + (f * 64 + lane) * 8);
        wB[f] = *(const short8*)(wfb + (f * 64 + lane) * 8);
    }
    float biasA[4], biasB[4];
    #pragma unroll
    for (int nt = 0; nt < 4; ++nt) {
        biasA[nt] = ba[nt * 16 + l15];
        biasB[nt] = bb[nt * 16 + l15];
    }

    const int arow = valid ? (rowbase + l15) : 0;
    const short8 a0 = *(const short8*)(z + arow * 64 + quad * 8);
    const short8 a1 = *(const short8*)(z + arow * 64 + 32 + quad * 8);

    f32x4 acc[4];
    #pragma unroll
    for (int nt = 0; nt < 4; ++nt) {
        f32x4 c = {0.f, 0.f, 0.f, 0.f};
        c = __builtin_amdgcn_mfma_f32_16x16x32_bf16(a0, wA[nt], c, 0, 0, 0);
        c = __builtin_amdgcn_mfma_f32_16x16x32_bf16(a1, wA[4 + nt], c, 0, 0, 0);
        acc[nt] = c;
    }
    #pragma unroll
    for (int nt = 0; nt < 4; ++nt)
        #pragma unroll
        for (int r = 0; r < 4; ++r)
            ldsT[wave][quad * 4 + r][nt * 16 + l15] =
                f2b(fmaxf(acc[nt][r] + biasA[nt], 0.f));

    const short8 y0 = *(const short8*)(&ldsT[wave][l15][quad * 8]);
    const short8 y1 = *(const short8*)(&ldsT[wave][l15][32 + quad * 8]);

    #pragma unroll
    for (int nt = 0; nt < 4; ++nt) {
        f32x4 c = {0.f, 0.f, 0.f, 0.f};
        c = __builtin_amdgcn_mfma_f32_16x16x32_bf16(y0, wB[nt], c, 0, 0, 0);
        c = __builtin_amdgcn_mfma_f32_16x16x32_bf16(y1, wB[4 + nt], c, 0, 0, 0);
        acc[nt] = c;
    }
    #pragma unroll
    for (int nt = 0; nt < 4; ++nt)
        #pragma unroll
        for (int r = 0; r < 4; ++r)
            ldsT[wave][quad * 4 + r][nt * 16 + l15] =
                f2b(fmaxf(acc[nt][r] + biasB[nt], 0.f));

    // BN partials (wave reads its own region; same-wave ordered)
    {
        float s = 0.f, sq = 0.f;
        if (valid) {
            #pragma unroll 4
            for (int r = 0; r < 16; ++r) {
                const float v = b2f(ldsT[wave][r][lane]);
                s += v;
                sq += v * v;
            }
        }
        red[wave * 128 + lane] = s;
        red[wave * 128 + 64 + lane] = sq;
    }
    __syncthreads();

    if (threadIdx.x < 128) {
        const float tot = red[threadIdx.x] + red[128 + threadIdx.x] +
                          red[256 + threadIdx.x] + red[384 + threadIdx.x];
        atomicAdd(&stats[(blockIdx.x & 7) * 128 + threadIdx.x], tot);
    }

    #pragma unroll
    for (int m = 0; m < 4; ++m) {
        const int g = m * 256 + threadIdx.x;     // 1024 groups of 4 feats
        const int r = g >> 4;
        const int f4 = (g & 15) * 4;
        const int grow = blockIdx.x * 64 + r;
        if (grow < NN)
            *(ushort4*)(tout + grow * 64 + f4) =
                *(const ushort4*)(&ldsT[r >> 4][r & 15][f4]);
    }
}

// ===========================================================================
// Pool (bf16 t in, layer-3 BN finalize folded into preamble); batch sorted.
// ===========================================================================
__global__ __launch_bounds__(256) void pool_kernel(const unsigned short* __restrict__ t,
                                                   const int* __restrict__ batch,
                                                   const float* __restrict__ stats,
                                                   const float* __restrict__ ga,
                                                   const float* __restrict__ be,
                                                   float* __restrict__ xpool) {
    const int wv = (blockIdx.x * 256 + threadIdx.x) >> 6;
    const int lane = threadIdx.x & 63;

    float s = 0.f, sq = 0.f;
    #pragma unroll
    for (int k = 0; k < 8; ++k) {
        s += stats[k * 128 + lane];
        sq += stats[k * 128 + 64 + lane];
    }
    const float mean = s * (1.0f / NN);
    const float var = sq * (1.0f / NN) - mean * mean;
    const float scl = ga[lane] * rsqrtf(var + 1e-5f);
    const float sft = be[lane] - mean * scl;

    const int r0 = wv * 64;
    if (r0 >= NN) return;
    const int r1 = min(r0 + 64, NN);
    int gprev = batch[r0];
    float acc = 0.f;
    for (int r = r0; r < r1; ++r) {
        const int g = batch[r];
        if (g != gprev) {
            __hip_atomic_fetch_add(&xpool[gprev * 64 + lane], acc,
                                   __ATOMIC_RELAXED, __HIP_MEMORY_SCOPE_AGENT);
            acc = 0.f;
            gprev = g;
        }
        acc += fmaf(b2f(t[r * 64 + lane]), scl, sft);
    }
    __hip_atomic_fetch_add(&xpool[gprev * 64 + lane], acc,
                           __ATOMIC_RELAXED, __HIP_MEMORY_SCOPE_AGENT);
}

// ===========================================================================
// Fused head: out[g] = relu((xpool[g] @ w0 + b0) @ w1 + b1). One block per g.
// ===========================================================================
__global__ __launch_bounds__(128) void head_kernel(const float* __restrict__ xpool,
                                                   const float* __restrict__ w0,
                                                   const float* __restrict__ b0,
                                                   const float* __restrict__ w1,
                                                   const float* __restrict__ b1,
                                                   float* __restrict__ out) {
    __shared__ float xp[64];
    __shared__ float midl[128];
    const int g = blockIdx.x;
    const int t = threadIdx.x;
    if (t < 64) xp[t] = xpool[g * 64 + t];
    __syncthreads();
    float acc = b0[t];
    #pragma unroll 8
    for (int k = 0; k < 64; ++k) acc = fmaf(xp[k], w0[k * 128 + t], acc);
    midl[t] = acc;
    __syncthreads();
    if (t < 64) {
        float a2 = b1[t];
        #pragma unroll 8
        for (int k = 0; k < 128; ++k) a2 = fmaf(midl[k], w1[k * 64 + t], a2);
        out[g * 64 + t] = fmaxf(a2, 0.f);
    }
}

extern "C" void kernel_launch(void* const* d_in, const int* in_sizes, int n_in,
                              void* d_out, int out_size, void* d_ws, size_t ws_size,
                              hipStream_t stream) {
    const float* x = (const float*)d_in[0];
    const int* ei = (const int*)d_in[1];
    const int* batch = (const int*)d_in[2];

    // ---- workspace layout ----
    int* ibase   = (int*)d_ws;
    int* counts  = ibase;            // 50000 (int4-zeroable)
    int* scanned = ibase + 50000;    // 50000
    int* rowptr  = ibase + 100000;   // 50001 (pad to 50004)
    int* cursor  = ibase + 150004;   // 50000
    int* bsum    = ibase + 200004;   // 128 (98 used)
    int* col     = ibase + 200132;   // 800000 -> int end 1,000,132 (pad 1,000,192)
    float* fbase = (float*)d_ws + 1000192;       // 16B aligned
    float* stats = fbase;                        // 3 x 1024 = 3072
    float* xpool = stats + 3072;                 // 32768 (zeroed by prep)
    unsigned short* zbf  = (unsigned short*)(fbase + 35856 + 128);  // NN*64
    unsigned short* xbf  = zbf + 3200000;
    unsigned short* t0bf = xbf + 3200000;
    unsigned short* t1bf = t0bf + 3200000;
    unsigned short* wfrag = t1bf + 3200000;      // 6 x 4096 bf16

    // ---- prep (x->bf16 + zeroing + weight swizzle) + CSR build ----
    prep_kernel<<<3215, 256, 0, stream>>>(x, xbf, counts, stats,
                                          (const float*)d_in[3], (const float*)d_in[5],
                                          (const float*)d_in[9], (const float*)d_in[11],
                                          (const float*)d_in[15], (const float*)d_in[17],
                                          wfrag);
    hist_kernel<<<(EE + 255) / 256, 256, 0, stream>>>(ei, counts);
    scan1_kernel<<<SCAN_BLOCKS, 512, 0, stream>>>(counts, scanned, bsum);
    scan2_kernel<<<SCAN_BLOCKS, 512, 0, stream>>>(scanned, bsum, rowptr, cursor);
    fill_kernel<<<2048, 256, 0, stream>>>(ei, cursor, col);

    // ---- 3 GIN layers: gather (folded finalize) + MFMA mlp ----
    const unsigned short* hcur = xbf;
    unsigned short* touts[3] = {t0bf, t1bf, t0bf};
    for (int l = 0; l < 3; ++l) {
        const float* ba = (const float*)d_in[3 + l * 6 + 1];
        const float* bb = (const float*)d_in[3 + l * 6 + 3];
        const float* gp = (const float*)d_in[3 + (l ? (l - 1) : 0) * 6 + 4];
        const float* bp = (const float*)d_in[3 + (l ? (l - 1) : 0) * 6 + 5];

        gather_kernel<<<12500, 256, 0, stream>>>(hcur, rowptr, col,
                                                 stats + (l ? (l - 1) : 0) * 1024,
                                                 gp, bp, l > 0, zbf);
        mlp_kernel<<<TILES, 256, 0, stream>>>(zbf,
                                              wfrag + (l * 2 + 0) * 4096, ba,
                                              wfrag + (l * 2 + 1) * 4096, bb,
                                              touts[l], stats + l * 1024);
        hcur = touts[l];
    }

    pool_kernel<<<(TILES + 3) / 4, 256, 0, stream>>>(
        t0bf, batch, stats + 2048,
        (const float*)d_in[19], (const float*)d_in[20], xpool);
    head_kernel<<<GG, 128, 0, stream>>>(
        xpool, (const float*)d_in[21], (const float*)d_in[22],
        (const float*)d_in[23], (const float*)d_in[24], (float*)d_out);
}